// Round 8
// baseline (290.085 us; speedup 1.0000x reference)
//
#include <hip/hip_runtime.h>

#define GN_EPS 1e-8f

static constexpr int F     = 64;   // features
static constexpr int G     = 8;    // groups (group of channel f is f & 7 due to reshape(-1, G))
static constexpr int NB    = 16;   // batches
static constexpr int BLK   = 256;
static constexpr int GRID  = 1024; // 4 blocks/CU guaranteed by __launch_bounds__(256,4) -> all co-resident
static constexpr int NSLOT = 16;   // shadow accumulator copies

typedef float f32x4 __attribute__((ext_vector_type(4)));

// ws layout: gsum[NSLOT][NB*G] | gsq[NSLOT][NB*G] | bar (int)
// hipMemsetAsync zeroes all of it before the kernel on every call (incl. every
// graph replay) -> accumulators zeroed AND barrier counter reset deterministically.

#define ACC4(v)                          \
    s0 += (v).x; q0 = fmaf((v).x, (v).x, q0); \
    s1 += (v).y; q1 = fmaf((v).y, (v).y, q1); \
    s2 += (v).z; q2 = fmaf((v).z, (v).z, q2); \
    s3 += (v).w; q3 = fmaf((v).w, (v).w, q3);

__global__ __launch_bounds__(BLK, 4) void gn_fused(
        const float* __restrict__ feats, const int* __restrict__ ids, int n,
        float* __restrict__ gsum, float* __restrict__ gsq, int* __restrict__ bar,
        const float* __restrict__ gamma, const float* __restrict__ beta,
        float* __restrict__ out) {
    __shared__ float lsum[NB * G];
    __shared__ float lsq [NB * G];
    __shared__ int   soff[NB + 1];
    const int t = threadIdx.x;

    // ---- phase 0: per-block replicated binary-search offsets (ids sorted) ----
    if (t < NB + 1) {
        int lo = 0, hi = n;
        while (lo < hi) {
            int mid = (lo + hi) >> 1;
            if (ids[mid] < t) lo = mid + 1; else hi = mid;
        }
        soff[t] = lo;   // first row with id >= t
    }
    if (t < NB * G) { lsum[t] = 0.f; lsq[t] = 0.f; }
    __syncthreads();

    const int rpb  = (n + GRID - 1) / GRID;
    const int row0 = (int)blockIdx.x * rpb;
    const int row1 = min(n, row0 + rpb);
    const int quad   = t & 15;
    const int subrow = t >> 4;
    const int lane   = t & 63;

    // ---- phase 1: per-(batch,group) sum/sumsq over own chunk (8 loads in flight) ----
    if (row0 < row1) {
        int b = 0, cur = row0;
        while (cur < row1) {
            while (soff[b + 1] <= cur) ++b;          // batch of this segment
            const int send = min(row1, soff[b + 1]); // segment end (block-uniform)
            float s0=0.f,s1=0.f,s2=0.f,s3=0.f,q0=0.f,q1=0.f,q2=0.f,q3=0.f;
            const float* p = feats + (size_t)(cur + subrow) * F + quad * 4;
            int base = cur;
            for (; base + 128 <= send; base += 128, p += 128 * F) {   // 128-row tiles
                const float4 x0 = *reinterpret_cast<const float4*>(p);
                const float4 x1 = *reinterpret_cast<const float4*>(p + 16 * F);
                const float4 x2 = *reinterpret_cast<const float4*>(p + 32 * F);
                const float4 x3 = *reinterpret_cast<const float4*>(p + 48 * F);
                const float4 x4 = *reinterpret_cast<const float4*>(p + 64 * F);
                const float4 x5 = *reinterpret_cast<const float4*>(p + 80 * F);
                const float4 x6 = *reinterpret_cast<const float4*>(p + 96 * F);
                const float4 x7 = *reinterpret_cast<const float4*>(p + 112 * F);
                ACC4(x0) ACC4(x1) ACC4(x2) ACC4(x3)
                ACC4(x4) ACC4(x5) ACC4(x6) ACC4(x7)
            }
            for (; base + 16 <= send; base += 16, p += 16 * F) {
                const float4 x = *reinterpret_cast<const float4*>(p);
                ACC4(x)
            }
            if (base + subrow < send) {              // segment tail (<16 rows)
                const float4 x = *reinterpret_cast<const float4*>(p);
                ACC4(x)
            }
            // butterfly over lane-bits 1..5: lane0 -> groups 0..3, lane1 -> groups 4..7
            #pragma unroll
            for (int m = 2; m <= 32; m <<= 1) {
                s0 += __shfl_xor(s0, m); s1 += __shfl_xor(s1, m);
                s2 += __shfl_xor(s2, m); s3 += __shfl_xor(s3, m);
                q0 += __shfl_xor(q0, m); q1 += __shfl_xor(q1, m);
                q2 += __shfl_xor(q2, m); q3 += __shfl_xor(q3, m);
            }
            if (lane < 2) {
                float* ps = &lsum[b * G + lane * 4];
                float* pq = &lsq [b * G + lane * 4];
                atomicAdd(ps + 0, s0); atomicAdd(ps + 1, s1);
                atomicAdd(ps + 2, s2); atomicAdd(ps + 3, s3);
                atomicAdd(pq + 0, q0); atomicAdd(pq + 1, q1);
                atomicAdd(pq + 2, q2); atomicAdd(pq + 3, q3);
            }
            cur = send;
        }
    }
    __syncthreads();
    if (t < NB * G) {
        const int slot = (int)blockIdx.x & (NSLOT - 1);
        atomicAdd(&gsum[slot * NB * G + t], lsum[t]);   // device-scope -> coherence point
        atomicAdd(&gsq [slot * NB * G + t], lsq [t]);
    }

    // ---- software grid barrier (counter reset by the memset before launch) ----
    __syncthreads();               // all global atomics above are complete (vmcnt drain)
    if (t == 0) {
        __threadfence();
        __hip_atomic_fetch_add(bar, 1, __ATOMIC_RELEASE, __HIP_MEMORY_SCOPE_AGENT);
        while (__hip_atomic_load(bar, __ATOMIC_ACQUIRE, __HIP_MEMORY_SCOPE_AGENT) < GRID)
            __builtin_amdgcn_s_sleep(2);
    }
    __syncthreads();

    // ---- phase 2: normalize own chunk, backward (own L2/L3-resident tail first) ----
    if (row0 >= row1) return;
    const float4 gm = *reinterpret_cast<const float4*>(gamma + quad * 4);
    const float4 bt = *reinterpret_cast<const float4*>(beta  + quad * 4);

    int b = NB - 1, e = row1;
    while (e > row0) {
        while (soff[b] >= e) --b;                 // rows e-1 belong to batch b
        const int sstart = max(row0, soff[b]);    // segment = [sstart, e), uniform b
        // sum the NSLOT shadow copies; agent-scope atomic loads -> immune to any
        // stale per-XCD L2 line (cheap: once per segment).
        f32x4 sm = {0.f, 0.f, 0.f, 0.f}, sq = {0.f, 0.f, 0.f, 0.f};
        #pragma unroll
        for (int k = 0; k < NSLOT; ++k) {
            const float* ps = gsum + k * NB * G + b * G + (quad & 1) * 4;
            const float* pq = gsq  + k * NB * G + b * G + (quad & 1) * 4;
            sm.x += __hip_atomic_load(ps + 0, __ATOMIC_RELAXED, __HIP_MEMORY_SCOPE_AGENT);
            sm.y += __hip_atomic_load(ps + 1, __ATOMIC_RELAXED, __HIP_MEMORY_SCOPE_AGENT);
            sm.z += __hip_atomic_load(ps + 2, __ATOMIC_RELAXED, __HIP_MEMORY_SCOPE_AGENT);
            sm.w += __hip_atomic_load(ps + 3, __ATOMIC_RELAXED, __HIP_MEMORY_SCOPE_AGENT);
            sq.x += __hip_atomic_load(pq + 0, __ATOMIC_RELAXED, __HIP_MEMORY_SCOPE_AGENT);
            sq.y += __hip_atomic_load(pq + 1, __ATOMIC_RELAXED, __HIP_MEMORY_SCOPE_AGENT);
            sq.z += __hip_atomic_load(pq + 2, __ATOMIC_RELAXED, __HIP_MEMORY_SCOPE_AGENT);
            sq.w += __hip_atomic_load(pq + 3, __ATOMIC_RELAXED, __HIP_MEMORY_SCOPE_AGENT);
        }
        const float cnt = (float)max((soff[b + 1] - soff[b]) * (F / G), 1);
        const float rc  = 1.0f / cnt;
        f32x4 a, c;
        {
            const float m0 = sm.x * rc, m1 = sm.y * rc, m2 = sm.z * rc, m3 = sm.w * rc;
            const float v0 = fmaxf(sq.x * rc - m0 * m0, 0.f);
            const float v1 = fmaxf(sq.y * rc - m1 * m1, 0.f);
            const float v2 = fmaxf(sq.z * rc - m2 * m2, 0.f);
            const float v3 = fmaxf(sq.w * rc - m3 * m3, 0.f);
            a.x = gm.x / sqrtf(v0 + GN_EPS); a.y = gm.y / sqrtf(v1 + GN_EPS);
            a.z = gm.z / sqrtf(v2 + GN_EPS); a.w = gm.w / sqrtf(v3 + GN_EPS);
            c.x = fmaf(-m0, a.x, bt.x); c.y = fmaf(-m1, a.y, bt.y);
            c.z = fmaf(-m2, a.z, bt.z); c.w = fmaf(-m3, a.w, bt.w);
        }
        int hi = e;
        for (; hi - sstart >= 128; hi -= 128) {   // 128-row tiles, descending, 8 in flight
            const float* p  = feats + (size_t)(hi - 128 + subrow) * F + quad * 4;
            float*       po = out   + (size_t)(hi - 128 + subrow) * F + quad * 4;
            const f32x4 x0 = *reinterpret_cast<const f32x4*>(p);
            const f32x4 x1 = *reinterpret_cast<const f32x4*>(p + 16 * F);
            const f32x4 x2 = *reinterpret_cast<const f32x4*>(p + 32 * F);
            const f32x4 x3 = *reinterpret_cast<const f32x4*>(p + 48 * F);
            const f32x4 x4 = *reinterpret_cast<const f32x4*>(p + 64 * F);
            const f32x4 x5 = *reinterpret_cast<const f32x4*>(p + 80 * F);
            const f32x4 x6 = *reinterpret_cast<const f32x4*>(p + 96 * F);
            const f32x4 x7 = *reinterpret_cast<const f32x4*>(p + 112 * F);
            f32x4 o0, o1, o2, o3, o4, o5, o6, o7;
            o0.x = fmaf(x0.x, a.x, c.x); o0.y = fmaf(x0.y, a.y, c.y);
            o0.z = fmaf(x0.z, a.z, c.z); o0.w = fmaf(x0.w, a.w, c.w);
            o1.x = fmaf(x1.x, a.x, c.x); o1.y = fmaf(x1.y, a.y, c.y);
            o1.z = fmaf(x1.z, a.z, c.z); o1.w = fmaf(x1.w, a.w, c.w);
            o2.x = fmaf(x2.x, a.x, c.x); o2.y = fmaf(x2.y, a.y, c.y);
            o2.z = fmaf(x2.z, a.z, c.z); o2.w = fmaf(x2.w, a.w, c.w);
            o3.x = fmaf(x3.x, a.x, c.x); o3.y = fmaf(x3.y, a.y, c.y);
            o3.z = fmaf(x3.z, a.z, c.z); o3.w = fmaf(x3.w, a.w, c.w);
            o4.x = fmaf(x4.x, a.x, c.x); o4.y = fmaf(x4.y, a.y, c.y);
            o4.z = fmaf(x4.z, a.z, c.z); o4.w = fmaf(x4.w, a.w, c.w);
            o5.x = fmaf(x5.x, a.x, c.x); o5.y = fmaf(x5.y, a.y, c.y);
            o5.z = fmaf(x5.z, a.z, c.z); o5.w = fmaf(x5.w, a.w, c.w);
            o6.x = fmaf(x6.x, a.x, c.x); o6.y = fmaf(x6.y, a.y, c.y);
            o6.z = fmaf(x6.z, a.z, c.z); o6.w = fmaf(x6.w, a.w, c.w);
            o7.x = fmaf(x7.x, a.x, c.x); o7.y = fmaf(x7.y, a.y, c.y);
            o7.z = fmaf(x7.z, a.z, c.z); o7.w = fmaf(x7.w, a.w, c.w);
            __builtin_nontemporal_store(o0, reinterpret_cast<f32x4*>(po));
            __builtin_nontemporal_store(o1, reinterpret_cast<f32x4*>(po + 16 * F));
            __builtin_nontemporal_store(o2, reinterpret_cast<f32x4*>(po + 32 * F));
            __builtin_nontemporal_store(o3, reinterpret_cast<f32x4*>(po + 48 * F));
            __builtin_nontemporal_store(o4, reinterpret_cast<f32x4*>(po + 64 * F));
            __builtin_nontemporal_store(o5, reinterpret_cast<f32x4*>(po + 80 * F));
            __builtin_nontemporal_store(o6, reinterpret_cast<f32x4*>(po + 96 * F));
            __builtin_nontemporal_store(o7, reinterpret_cast<f32x4*>(po + 112 * F));
        }
        for (; hi - sstart >= 16; hi -= 16) {     // 16-row tiles, descending
            const float* p  = feats + (size_t)(hi - 16 + subrow) * F + quad * 4;
            float*       po = out   + (size_t)(hi - 16 + subrow) * F + quad * 4;
            const f32x4 x = *reinterpret_cast<const f32x4*>(p);
            f32x4 o;
            o.x = fmaf(x.x, a.x, c.x); o.y = fmaf(x.y, a.y, c.y);
            o.z = fmaf(x.z, a.z, c.z); o.w = fmaf(x.w, a.w, c.w);
            __builtin_nontemporal_store(o, reinterpret_cast<f32x4*>(po));
        }
        if (sstart + subrow < hi) {               // bottom tail (<16 rows)
            const float* p  = feats + (size_t)(sstart + subrow) * F + quad * 4;
            float*       po = out   + (size_t)(sstart + subrow) * F + quad * 4;
            const f32x4 x = *reinterpret_cast<const f32x4*>(p);
            f32x4 o;
            o.x = fmaf(x.x, a.x, c.x); o.y = fmaf(x.y, a.y, c.y);
            o.z = fmaf(x.z, a.z, c.z); o.w = fmaf(x.w, a.w, c.w);
            __builtin_nontemporal_store(o, reinterpret_cast<f32x4*>(po));
        }
        e = sstart;
    }
}

extern "C" void kernel_launch(void* const* d_in, const int* in_sizes, int n_in,
                              void* d_out, int out_size, void* d_ws, size_t ws_size,
                              hipStream_t stream) {
    const float* feats = (const float*)d_in[0];
    const int*   ids   = (const int*)  d_in[1];
    const float* gamma = (const float*)d_in[2];
    const float* beta  = (const float*)d_in[3];
    const int n = in_sizes[1];                     // N rows (batch_ids count)

    float* gsum = (float*)d_ws;                    // [NSLOT][NB*G]
    float* gsq  = gsum + NSLOT * NB * G;           // [NSLOT][NB*G]
    int*   bar  = (int*)(gsq + NSLOT * NB * G);    // barrier counter

    // Zero accumulators + barrier counter before every kernel run (graph replays
    // re-execute this memset, keeping the launch deterministic call-to-call).
    hipMemsetAsync(d_ws, 0, (2 * NSLOT * NB * G) * sizeof(float) + sizeof(int), stream);
    gn_fused<<<GRID, BLK, 0, stream>>>(feats, ids, n, gsum, gsq, bar,
                                       gamma, beta, (float*)d_out);
}

// Round 9
// 252.737 us; speedup vs baseline: 1.1478x; 1.1478x over previous
//
#include <hip/hip_runtime.h>

#define GN_EPS 1e-8f

static constexpr int F     = 64;   // features
static constexpr int G     = 8;    // groups (group of channel f is f & 7 due to reshape(-1, G))
static constexpr int NB    = 16;   // batches
static constexpr int BLK   = 256;
static constexpr int GRID  = 1024; // 4 blocks/CU guaranteed by __launch_bounds__(256,4)
static constexpr int NSLOT = 16;   // shadow accumulator copies

typedef float f32x4 __attribute__((ext_vector_type(4)));

// ws layout: gsum[NSLOT][NB*G] | gsq[NSLOT][NB*G] | bar (int)
// hipMemsetAsync zeroes all of it before the kernel on every call (incl. every
// graph replay) -> accumulators zeroed AND barrier counter reset deterministically.

#define ACC4(v)                          \
    s0 += (v).x; q0 = fmaf((v).x, (v).x, q0); \
    s1 += (v).y; q1 = fmaf((v).y, (v).y, q1); \
    s2 += (v).z; q2 = fmaf((v).z, (v).z, q2); \
    s3 += (v).w; q3 = fmaf((v).w, (v).w, q3);

__global__ __launch_bounds__(BLK, 4) void gn_fused(
        const float* __restrict__ feats, const int* __restrict__ ids, int n,
        float* __restrict__ gsum, float* __restrict__ gsq, int* __restrict__ bar,
        const float* __restrict__ gamma, const float* __restrict__ beta,
        float* __restrict__ out) {
    __shared__ float lsum[NB * G];
    __shared__ float lsq [NB * G];
    __shared__ int   soff[NB + 1];
    const int t = threadIdx.x;

    // ---- phase 0: per-block replicated binary-search offsets (ids sorted) ----
    if (t < NB + 1) {
        int lo = 0, hi = n;
        while (lo < hi) {
            int mid = (lo + hi) >> 1;
            if (ids[mid] < t) lo = mid + 1; else hi = mid;
        }
        soff[t] = lo;   // first row with id >= t
    }
    if (t < NB * G) { lsum[t] = 0.f; lsq[t] = 0.f; }
    __syncthreads();

    const int rpb  = (n + GRID - 1) / GRID;
    const int row0 = (int)blockIdx.x * rpb;
    const int row1 = min(n, row0 + rpb);
    const int quad   = t & 15;
    const int subrow = t >> 4;
    const int lane   = t & 63;

    // ---- phase 1: per-(batch,group) sum/sumsq over own chunk (depth-4 MLP) ----
    if (row0 < row1) {
        int b = 0, cur = row0;
        while (cur < row1) {
            while (soff[b + 1] <= cur) ++b;          // batch of this segment
            const int send = min(row1, soff[b + 1]); // segment end (block-uniform)
            float s0=0.f,s1=0.f,s2=0.f,s3=0.f,q0=0.f,q1=0.f,q2=0.f,q3=0.f;
            const float* p = feats + (size_t)(cur + subrow) * F + quad * 4;
            int base = cur;
            for (; base + 64 <= send; base += 64, p += 64 * F) {   // 64-row tiles
                const float4 x0 = *reinterpret_cast<const float4*>(p);
                const float4 x1 = *reinterpret_cast<const float4*>(p + 16 * F);
                const float4 x2 = *reinterpret_cast<const float4*>(p + 32 * F);
                const float4 x3 = *reinterpret_cast<const float4*>(p + 48 * F);
                ACC4(x0) ACC4(x1) ACC4(x2) ACC4(x3)
            }
            for (; base + 16 <= send; base += 16, p += 16 * F) {
                const float4 x = *reinterpret_cast<const float4*>(p);
                ACC4(x)
            }
            if (base + subrow < send) {              // segment tail (<16 rows)
                const float4 x = *reinterpret_cast<const float4*>(p);
                ACC4(x)
            }
            // butterfly over lane-bits 1..5: lane0 -> groups 0..3, lane1 -> groups 4..7
            #pragma unroll
            for (int m = 2; m <= 32; m <<= 1) {
                s0 += __shfl_xor(s0, m); s1 += __shfl_xor(s1, m);
                s2 += __shfl_xor(s2, m); s3 += __shfl_xor(s3, m);
                q0 += __shfl_xor(q0, m); q1 += __shfl_xor(q1, m);
                q2 += __shfl_xor(q2, m); q3 += __shfl_xor(q3, m);
            }
            if (lane < 2) {
                float* ps = &lsum[b * G + lane * 4];
                float* pq = &lsq [b * G + lane * 4];
                atomicAdd(ps + 0, s0); atomicAdd(ps + 1, s1);
                atomicAdd(ps + 2, s2); atomicAdd(ps + 3, s3);
                atomicAdd(pq + 0, q0); atomicAdd(pq + 1, q1);
                atomicAdd(pq + 2, q2); atomicAdd(pq + 3, q3);
            }
            cur = send;
        }
    }
    __syncthreads();
    if (t < NB * G) {
        const int slot = (int)blockIdx.x & (NSLOT - 1);
        atomicAdd(&gsum[slot * NB * G + t], lsum[t]);   // device-scope -> coherence point
        atomicAdd(&gsq [slot * NB * G + t], lsq [t]);
    }

    // ---- software grid barrier: release-add once, then RELAXED low-rate poll ----
    __syncthreads();               // all global atomics above complete (vmcnt drain)
    if (t == 0) {
        __threadfence();
        __hip_atomic_fetch_add(bar, 1, __ATOMIC_RELEASE, __HIP_MEMORY_SCOPE_AGENT);
        // relaxed poll: no acquire/invalidate per iteration; ~2k cycles between polls
        while (__hip_atomic_load(bar, __ATOMIC_RELAXED, __HIP_MEMORY_SCOPE_AGENT) < GRID)
            __builtin_amdgcn_s_sleep(32);
        __threadfence();           // one ordering point after the barrier opens
    }
    __syncthreads();

    // ---- phase 2: normalize own chunk, backward (own L2/L3-resident tail first) ----
    if (row0 >= row1) return;
    const float4 gm = *reinterpret_cast<const float4*>(gamma + quad * 4);
    const float4 bt = *reinterpret_cast<const float4*>(beta  + quad * 4);

    int b = NB - 1, e = row1;
    while (e > row0) {
        while (soff[b] >= e) --b;                 // rows e-1 belong to batch b
        const int sstart = max(row0, soff[b]);    // segment = [sstart, e), uniform b
        // sum the NSLOT shadow copies; agent-scope atomic loads read the coherence
        // point directly -> immune to stale per-XCD L2 lines (once per segment).
        f32x4 sm = {0.f, 0.f, 0.f, 0.f}, sq = {0.f, 0.f, 0.f, 0.f};
        #pragma unroll
        for (int k = 0; k < NSLOT; ++k) {
            const float* ps = gsum + k * NB * G + b * G + (quad & 1) * 4;
            const float* pq = gsq  + k * NB * G + b * G + (quad & 1) * 4;
            sm.x += __hip_atomic_load(ps + 0, __ATOMIC_RELAXED, __HIP_MEMORY_SCOPE_AGENT);
            sm.y += __hip_atomic_load(ps + 1, __ATOMIC_RELAXED, __HIP_MEMORY_SCOPE_AGENT);
            sm.z += __hip_atomic_load(ps + 2, __ATOMIC_RELAXED, __HIP_MEMORY_SCOPE_AGENT);
            sm.w += __hip_atomic_load(ps + 3, __ATOMIC_RELAXED, __HIP_MEMORY_SCOPE_AGENT);
            sq.x += __hip_atomic_load(pq + 0, __ATOMIC_RELAXED, __HIP_MEMORY_SCOPE_AGENT);
            sq.y += __hip_atomic_load(pq + 1, __ATOMIC_RELAXED, __HIP_MEMORY_SCOPE_AGENT);
            sq.z += __hip_atomic_load(pq + 2, __ATOMIC_RELAXED, __HIP_MEMORY_SCOPE_AGENT);
            sq.w += __hip_atomic_load(pq + 3, __ATOMIC_RELAXED, __HIP_MEMORY_SCOPE_AGENT);
        }
        const float cnt = (float)max((soff[b + 1] - soff[b]) * (F / G), 1);
        const float rc  = 1.0f / cnt;
        f32x4 a, c;
        {
            const float m0 = sm.x * rc, m1 = sm.y * rc, m2 = sm.z * rc, m3 = sm.w * rc;
            const float v0 = fmaxf(sq.x * rc - m0 * m0, 0.f);
            const float v1 = fmaxf(sq.y * rc - m1 * m1, 0.f);
            const float v2 = fmaxf(sq.z * rc - m2 * m2, 0.f);
            const float v3 = fmaxf(sq.w * rc - m3 * m3, 0.f);
            a.x = gm.x / sqrtf(v0 + GN_EPS); a.y = gm.y / sqrtf(v1 + GN_EPS);
            a.z = gm.z / sqrtf(v2 + GN_EPS); a.w = gm.w / sqrtf(v3 + GN_EPS);
            c.x = fmaf(-m0, a.x, bt.x); c.y = fmaf(-m1, a.y, bt.y);
            c.z = fmaf(-m2, a.z, bt.z); c.w = fmaf(-m3, a.w, bt.w);
        }
        int hi = e;
        for (; hi - sstart >= 64; hi -= 64) {     // 64-row tiles, descending, depth-4
            const float* p  = feats + (size_t)(hi - 64 + subrow) * F + quad * 4;
            float*       po = out   + (size_t)(hi - 64 + subrow) * F + quad * 4;
            const f32x4 x0 = *reinterpret_cast<const f32x4*>(p);
            const f32x4 x1 = *reinterpret_cast<const f32x4*>(p + 16 * F);
            const f32x4 x2 = *reinterpret_cast<const f32x4*>(p + 32 * F);
            const f32x4 x3 = *reinterpret_cast<const f32x4*>(p + 48 * F);
            f32x4 o0, o1, o2, o3;
            o0.x = fmaf(x0.x, a.x, c.x); o0.y = fmaf(x0.y, a.y, c.y);
            o0.z = fmaf(x0.z, a.z, c.z); o0.w = fmaf(x0.w, a.w, c.w);
            o1.x = fmaf(x1.x, a.x, c.x); o1.y = fmaf(x1.y, a.y, c.y);
            o1.z = fmaf(x1.z, a.z, c.z); o1.w = fmaf(x1.w, a.w, c.w);
            o2.x = fmaf(x2.x, a.x, c.x); o2.y = fmaf(x2.y, a.y, c.y);
            o2.z = fmaf(x2.z, a.z, c.z); o2.w = fmaf(x2.w, a.w, c.w);
            o3.x = fmaf(x3.x, a.x, c.x); o3.y = fmaf(x3.y, a.y, c.y);
            o3.z = fmaf(x3.z, a.z, c.z); o3.w = fmaf(x3.w, a.w, c.w);
            __builtin_nontemporal_store(o0, reinterpret_cast<f32x4*>(po));
            __builtin_nontemporal_store(o1, reinterpret_cast<f32x4*>(po + 16 * F));
            __builtin_nontemporal_store(o2, reinterpret_cast<f32x4*>(po + 32 * F));
            __builtin_nontemporal_store(o3, reinterpret_cast<f32x4*>(po + 48 * F));
        }
        for (; hi - sstart >= 16; hi -= 16) {     // 16-row tiles, descending
            const float* p  = feats + (size_t)(hi - 16 + subrow) * F + quad * 4;
            float*       po = out   + (size_t)(hi - 16 + subrow) * F + quad * 4;
            const f32x4 x = *reinterpret_cast<const f32x4*>(p);
            f32x4 o;
            o.x = fmaf(x.x, a.x, c.x); o.y = fmaf(x.y, a.y, c.y);
            o.z = fmaf(x.z, a.z, c.z); o.w = fmaf(x.w, a.w, c.w);
            __builtin_nontemporal_store(o, reinterpret_cast<f32x4*>(po));
        }
        if (sstart + subrow < hi) {               // bottom tail (<16 rows)
            const float* p  = feats + (size_t)(sstart + subrow) * F + quad * 4;
            float*       po = out   + (size_t)(sstart + subrow) * F + quad * 4;
            const f32x4 x = *reinterpret_cast<const f32x4*>(p);
            f32x4 o;
            o.x = fmaf(x.x, a.x, c.x); o.y = fmaf(x.y, a.y, c.y);
            o.z = fmaf(x.z, a.z, c.z); o.w = fmaf(x.w, a.w, c.w);
            __builtin_nontemporal_store(o, reinterpret_cast<f32x4*>(po));
        }
        e = sstart;
    }
}

extern "C" void kernel_launch(void* const* d_in, const int* in_sizes, int n_in,
                              void* d_out, int out_size, void* d_ws, size_t ws_size,
                              hipStream_t stream) {
    const float* feats = (const float*)d_in[0];
    const int*   ids   = (const int*)  d_in[1];
    const float* gamma = (const float*)d_in[2];
    const float* beta  = (const float*)d_in[3];
    const int n = in_sizes[1];                     // N rows (batch_ids count)

    float* gsum = (float*)d_ws;                    // [NSLOT][NB*G]
    float* gsq  = gsum + NSLOT * NB * G;           // [NSLOT][NB*G]
    int*   bar  = (int*)(gsq + NSLOT * NB * G);    // barrier counter

    // Zero accumulators + barrier counter before every kernel run (graph replays
    // re-execute this memset, keeping the launch deterministic call-to-call).
    hipMemsetAsync(d_ws, 0, (2 * NSLOT * NB * G) * sizeof(float) + sizeof(int), stream);
    gn_fused<<<GRID, BLK, 0, stream>>>(feats, ids, n, gsum, gsq, bar,
                                       gamma, beta, (float*)d_out);
}

// Round 10
// 137.626 us; speedup vs baseline: 2.1078x; 1.8364x over previous
//
#include <hip/hip_runtime.h>

#define GN_EPS 1e-8f

static constexpr int F     = 64;   // features
static constexpr int G     = 8;    // groups (group of channel f is f & 7 due to reshape(-1, G))
static constexpr int NB    = 16;   // batches
static constexpr int BLK   = 256;
static constexpr int GRID  = 2048; // 8 blocks/CU, 32 waves/CU — proven 6+ TB/s config (R4/R5)
static constexpr int NSLOT = 16;   // shadow accumulator copies (atomic contention 2048 -> 128)

typedef float f32x4 __attribute__((ext_vector_type(4)));

// ws layout: gsum[NSLOT][NB*G] | gsq[NSLOT][NB*G]  (16 KB, zeroed by memsetAsync each call)

// Per-block replicated offset search (ids sorted): 17 lanes, ~20 L2-hit loads.
// Validated in R7-R9. Removes the gn_prep dispatch and the off[] global round-trip.
__device__ __forceinline__ void block_offsets(const int* __restrict__ ids, int n,
                                              int* __restrict__ soff, int t) {
    if (t < NB + 1) {
        int lo = 0, hi = n;
        while (lo < hi) {
            int mid = (lo + hi) >> 1;
            if (ids[mid] < t) lo = mid + 1; else hi = mid;
        }
        soff[t] = lo;   // first row with id >= t; soff[0]=0, soff[NB]=n
    }
}

// --- Kernel A: per-(batch,group) sum/sumsq, segment-uniform inner loop ---
// 16 threads/row (float4 each); 64-row tiles = 4 independent loads/lane/iter.
// Element j of the float4 at feature quad*4+j belongs to group (quad&1)*4 + j.
__global__ __launch_bounds__(BLK) void gn_stats(
        const float* __restrict__ feats, const int* __restrict__ ids, int n,
        float* __restrict__ gsum, float* __restrict__ gsq) {
    __shared__ float lsum[NB * G];
    __shared__ float lsq [NB * G];
    __shared__ int   soff[NB + 1];
    const int t = threadIdx.x;
    block_offsets(ids, n, soff, t);
    if (t < NB * G) { lsum[t] = 0.f; lsq[t] = 0.f; }
    __syncthreads();

    const int rpb  = (n + GRID - 1) / GRID;
    const int row0 = (int)blockIdx.x * rpb;
    const int row1 = min(n, row0 + rpb);

    if (row0 < row1) {
        const int quad   = t & 15;
        const int subrow = t >> 4;
        const int lane   = t & 63;
        int b = 0, cur = row0;
        while (cur < row1) {
            while (soff[b + 1] <= cur) ++b;          // batch of this segment
            const int send = min(row1, soff[b + 1]); // segment end (block-uniform)
            float s0=0.f,s1=0.f,s2=0.f,s3=0.f,q0=0.f,q1=0.f,q2=0.f,q3=0.f;
            const float* p = feats + (size_t)(cur + subrow) * F + quad * 4;
            int base = cur;
            for (; base + 64 <= send; base += 64, p += 64 * F) {
                const float4 x0 = *reinterpret_cast<const float4*>(p);
                const float4 x1 = *reinterpret_cast<const float4*>(p + 16 * F);
                const float4 x2 = *reinterpret_cast<const float4*>(p + 32 * F);
                const float4 x3 = *reinterpret_cast<const float4*>(p + 48 * F);
                s0 += x0.x; q0 = fmaf(x0.x, x0.x, q0);
                s1 += x0.y; q1 = fmaf(x0.y, x0.y, q1);
                s2 += x0.z; q2 = fmaf(x0.z, x0.z, q2);
                s3 += x0.w; q3 = fmaf(x0.w, x0.w, q3);
                s0 += x1.x; q0 = fmaf(x1.x, x1.x, q0);
                s1 += x1.y; q1 = fmaf(x1.y, x1.y, q1);
                s2 += x1.z; q2 = fmaf(x1.z, x1.z, q2);
                s3 += x1.w; q3 = fmaf(x1.w, x1.w, q3);
                s0 += x2.x; q0 = fmaf(x2.x, x2.x, q0);
                s1 += x2.y; q1 = fmaf(x2.y, x2.y, q1);
                s2 += x2.z; q2 = fmaf(x2.z, x2.z, q2);
                s3 += x2.w; q3 = fmaf(x2.w, x2.w, q3);
                s0 += x3.x; q0 = fmaf(x3.x, x3.x, q0);
                s1 += x3.y; q1 = fmaf(x3.y, x3.y, q1);
                s2 += x3.z; q2 = fmaf(x3.z, x3.z, q2);
                s3 += x3.w; q3 = fmaf(x3.w, x3.w, q3);
            }
            for (; base + 16 <= send; base += 16, p += 16 * F) {
                const float4 x = *reinterpret_cast<const float4*>(p);
                s0 += x.x; q0 = fmaf(x.x, x.x, q0);
                s1 += x.y; q1 = fmaf(x.y, x.y, q1);
                s2 += x.z; q2 = fmaf(x.z, x.z, q2);
                s3 += x.w; q3 = fmaf(x.w, x.w, q3);
            }
            if (base + subrow < send) {              // segment tail (<16 rows)
                const float4 x = *reinterpret_cast<const float4*>(p);
                s0 += x.x; q0 = fmaf(x.x, x.x, q0);
                s1 += x.y; q1 = fmaf(x.y, x.y, q1);
                s2 += x.z; q2 = fmaf(x.z, x.z, q2);
                s3 += x.w; q3 = fmaf(x.w, x.w, q3);
            }
            // butterfly over lane-bits 1..5: lane0 -> groups 0..3, lane1 -> groups 4..7
            #pragma unroll
            for (int m = 2; m <= 32; m <<= 1) {
                s0 += __shfl_xor(s0, m); s1 += __shfl_xor(s1, m);
                s2 += __shfl_xor(s2, m); s3 += __shfl_xor(s3, m);
                q0 += __shfl_xor(q0, m); q1 += __shfl_xor(q1, m);
                q2 += __shfl_xor(q2, m); q3 += __shfl_xor(q3, m);
            }
            if (lane < 2) {
                float* ps = &lsum[b * G + lane * 4];
                float* pq = &lsq [b * G + lane * 4];
                atomicAdd(ps + 0, s0); atomicAdd(ps + 1, s1);
                atomicAdd(ps + 2, s2); atomicAdd(ps + 3, s3);
                atomicAdd(pq + 0, q0); atomicAdd(pq + 1, q1);
                atomicAdd(pq + 2, q2); atomicAdd(pq + 3, q3);
            }
            cur = send;
        }
    }
    __syncthreads();
    if (t < NB * G) {
        const int slot = (int)blockIdx.x & (NSLOT - 1);
        atomicAdd(&gsum[slot * NB * G + t], lsum[t]);
        atomicAdd(&gsq [slot * NB * G + t], lsq [t]);
    }
}

// --- Kernel B: normalize, REVERSED traversal (anti-LRU vs the output write
// stream; also picks up each XCD's L2 tail from stats). Per-segment register
// coefficients; hot loop = load float4 -> 4 fma -> nt store. ---
__global__ __launch_bounds__(BLK) void gn_norm(
        const float* __restrict__ feats, const int* __restrict__ ids, int n,
        const float* __restrict__ gsum, const float* __restrict__ gsq,
        const float* __restrict__ gamma, const float* __restrict__ beta,
        float* __restrict__ out) {
    __shared__ int soff[NB + 1];
    const int t = threadIdx.x;
    block_offsets(ids, n, soff, t);
    __syncthreads();

    const int rpb  = (n + GRID - 1) / GRID;
    const int row0 = (int)blockIdx.x * rpb;
    const int row1 = min(n, row0 + rpb);
    if (row0 >= row1) return;

    const int quad   = t & 15;
    const int subrow = t >> 4;
    const float4 gm = *reinterpret_cast<const float4*>(gamma + quad * 4);
    const float4 bt = *reinterpret_cast<const float4*>(beta  + quad * 4);

    int b = NB - 1, e = row1;
    while (e > row0) {
        while (soff[b] >= e) --b;                 // rows e-1 belong to batch b
        const int sstart = max(row0, soff[b]);    // segment = [sstart, e), uniform b
        // sum the NSLOT shadow copies for this lane's 4 groups ((quad&1)*4 ..+3);
        // kernel boundary after gn_stats is a full coherence point -> plain loads.
        f32x4 sm = {0.f, 0.f, 0.f, 0.f}, sq = {0.f, 0.f, 0.f, 0.f};
        #pragma unroll
        for (int k = 0; k < NSLOT; ++k) {
            sm += *reinterpret_cast<const f32x4*>(gsum + k * NB * G + b * G + (quad & 1) * 4);
            sq += *reinterpret_cast<const f32x4*>(gsq  + k * NB * G + b * G + (quad & 1) * 4);
        }
        const float cnt = (float)max((soff[b + 1] - soff[b]) * (F / G), 1);
        const float rc  = 1.0f / cnt;
        f32x4 a, c;
        {
            const float m0 = sm.x * rc, m1 = sm.y * rc, m2 = sm.z * rc, m3 = sm.w * rc;
            const float v0 = fmaxf(sq.x * rc - m0 * m0, 0.f);
            const float v1 = fmaxf(sq.y * rc - m1 * m1, 0.f);
            const float v2 = fmaxf(sq.z * rc - m2 * m2, 0.f);
            const float v3 = fmaxf(sq.w * rc - m3 * m3, 0.f);
            a.x = gm.x / sqrtf(v0 + GN_EPS); a.y = gm.y / sqrtf(v1 + GN_EPS);
            a.z = gm.z / sqrtf(v2 + GN_EPS); a.w = gm.w / sqrtf(v3 + GN_EPS);
            c.x = fmaf(-m0, a.x, bt.x); c.y = fmaf(-m1, a.y, bt.y);
            c.z = fmaf(-m2, a.z, bt.z); c.w = fmaf(-m3, a.w, bt.w);
        }
        int hi = e;
        for (; hi - sstart >= 64; hi -= 64) {     // 64-row tiles, descending
            const float* p  = feats + (size_t)(hi - 64 + subrow) * F + quad * 4;
            float*       po = out   + (size_t)(hi - 64 + subrow) * F + quad * 4;
            const f32x4 x0 = *reinterpret_cast<const f32x4*>(p);
            const f32x4 x1 = *reinterpret_cast<const f32x4*>(p + 16 * F);
            const f32x4 x2 = *reinterpret_cast<const f32x4*>(p + 32 * F);
            const f32x4 x3 = *reinterpret_cast<const f32x4*>(p + 48 * F);
            f32x4 o0, o1, o2, o3;
            o0.x = fmaf(x0.x, a.x, c.x); o0.y = fmaf(x0.y, a.y, c.y);
            o0.z = fmaf(x0.z, a.z, c.z); o0.w = fmaf(x0.w, a.w, c.w);
            o1.x = fmaf(x1.x, a.x, c.x); o1.y = fmaf(x1.y, a.y, c.y);
            o1.z = fmaf(x1.z, a.z, c.z); o1.w = fmaf(x1.w, a.w, c.w);
            o2.x = fmaf(x2.x, a.x, c.x); o2.y = fmaf(x2.y, a.y, c.y);
            o2.z = fmaf(x2.z, a.z, c.z); o2.w = fmaf(x2.w, a.w, c.w);
            o3.x = fmaf(x3.x, a.x, c.x); o3.y = fmaf(x3.y, a.y, c.y);
            o3.z = fmaf(x3.z, a.z, c.z); o3.w = fmaf(x3.w, a.w, c.w);
            __builtin_nontemporal_store(o0, reinterpret_cast<f32x4*>(po));
            __builtin_nontemporal_store(o1, reinterpret_cast<f32x4*>(po + 16 * F));
            __builtin_nontemporal_store(o2, reinterpret_cast<f32x4*>(po + 32 * F));
            __builtin_nontemporal_store(o3, reinterpret_cast<f32x4*>(po + 48 * F));
        }
        for (; hi - sstart >= 16; hi -= 16) {     // 16-row tiles, descending
            const float* p  = feats + (size_t)(hi - 16 + subrow) * F + quad * 4;
            float*       po = out   + (size_t)(hi - 16 + subrow) * F + quad * 4;
            const f32x4 x = *reinterpret_cast<const f32x4*>(p);
            f32x4 o;
            o.x = fmaf(x.x, a.x, c.x); o.y = fmaf(x.y, a.y, c.y);
            o.z = fmaf(x.z, a.z, c.z); o.w = fmaf(x.w, a.w, c.w);
            __builtin_nontemporal_store(o, reinterpret_cast<f32x4*>(po));
        }
        if (sstart + subrow < hi) {               // bottom tail (<16 rows)
            const float* p  = feats + (size_t)(sstart + subrow) * F + quad * 4;
            float*       po = out   + (size_t)(sstart + subrow) * F + quad * 4;
            const f32x4 x = *reinterpret_cast<const f32x4*>(p);
            f32x4 o;
            o.x = fmaf(x.x, a.x, c.x); o.y = fmaf(x.y, a.y, c.y);
            o.z = fmaf(x.z, a.z, c.z); o.w = fmaf(x.w, a.w, c.w);
            __builtin_nontemporal_store(o, reinterpret_cast<f32x4*>(po));
        }
        e = sstart;
    }
}

extern "C" void kernel_launch(void* const* d_in, const int* in_sizes, int n_in,
                              void* d_out, int out_size, void* d_ws, size_t ws_size,
                              hipStream_t stream) {
    const float* feats = (const float*)d_in[0];
    const int*   ids   = (const int*)  d_in[1];
    const float* gamma = (const float*)d_in[2];
    const float* beta  = (const float*)d_in[3];
    const int n = in_sizes[1];                     // N rows (batch_ids count)

    float* gsum = (float*)d_ws;                    // [NSLOT][NB*G]
    float* gsq  = gsum + NSLOT * NB * G;           // [NSLOT][NB*G]

    // ws is poisoned 0xAA and never re-poisoned between replays -> zero the
    // shadow accumulators every call (graph replays re-execute this memset).
    hipMemsetAsync(d_ws, 0, 2 * NSLOT * NB * G * sizeof(float), stream);
    gn_stats<<<GRID, BLK, 0, stream>>>(feats, ids, n, gsum, gsq);
    gn_norm <<<GRID, BLK, 0, stream>>>(feats, ids, n, gsum, gsq, gamma, beta, (float*)d_out);
}

// Round 11
// 129.890 us; speedup vs baseline: 2.2333x; 1.0596x over previous
//
#include <hip/hip_runtime.h>

#define GN_EPS 1e-8f

static constexpr int F     = 64;   // features
static constexpr int G     = 8;    // groups (group of channel f is f & 7 due to reshape(-1, G))
static constexpr int NB    = 16;   // batches
static constexpr int BLK   = 256;
static constexpr int GRID  = 2048; // 8 blocks/CU — proven 6+ TB/s streaming config (R4/R5)
static constexpr int NSLOT = 16;   // shadow accumulator copies (atomic contention 2048 -> 128)

typedef float f32x4 __attribute__((ext_vector_type(4)));

// ws layout: gsum[NSLOT][NB*G] | gsq[NSLOT][NB*G] | off[NB+1]

// --- Kernel A: zero shadow accumulators + per-batch offsets (ids sorted) ---
__global__ void gn_prep(const int* __restrict__ ids, int n, int* __restrict__ off,
                        float* __restrict__ zbuf /* 2*NSLOT*NB*G floats */) {
    const int t = threadIdx.x;
    for (int i = t; i < 2 * NSLOT * NB * G; i += BLK) zbuf[i] = 0.f;
    if (t < NB + 1) {
        int lo = 0, hi = n;
        while (lo < hi) {
            int mid = (lo + hi) >> 1;
            if (ids[mid] < t) lo = mid + 1; else hi = mid;
        }
        off[t] = lo;   // off[b] = first row with id >= b; off[0]=0, off[NB]=n
    }
}

// --- Kernel B: per-(batch,group) sum/sumsq, segment-uniform inner loop ---
// 16 threads/row (float4 each); 64-row tiles = 4 independent loads/lane/iter.
// Element j of the float4 at feature quad*4+j belongs to group (quad&1)*4 + j.
__global__ __launch_bounds__(BLK) void gn_stats(
        const float* __restrict__ feats, const int* __restrict__ off_g, int n,
        float* __restrict__ gsum, float* __restrict__ gsq) {
    __shared__ float lsum[NB * G];
    __shared__ float lsq [NB * G];
    __shared__ int   soff[NB + 1];
    const int t = threadIdx.x;
    if (t < NB * G) { lsum[t] = 0.f; lsq[t] = 0.f; }
    if (t < NB + 1) soff[t] = off_g[t];
    __syncthreads();

    const int rpb  = (n + GRID - 1) / GRID;
    const int row0 = (int)blockIdx.x * rpb;
    const int row1 = min(n, row0 + rpb);

    if (row0 < row1) {
        const int quad   = t & 15;
        const int subrow = t >> 4;
        const int lane   = t & 63;
        int b = 0, cur = row0;
        while (cur < row1) {
            while (soff[b + 1] <= cur) ++b;          // batch of this segment
            const int send = min(row1, soff[b + 1]); // segment end (block-uniform)
            float s0=0.f,s1=0.f,s2=0.f,s3=0.f,q0=0.f,q1=0.f,q2=0.f,q3=0.f;
            const float* p = feats + (size_t)(cur + subrow) * F + quad * 4;
            int base = cur;
            for (; base + 64 <= send; base += 64, p += 64 * F) {
                const float4 x0 = *reinterpret_cast<const float4*>(p);
                const float4 x1 = *reinterpret_cast<const float4*>(p + 16 * F);
                const float4 x2 = *reinterpret_cast<const float4*>(p + 32 * F);
                const float4 x3 = *reinterpret_cast<const float4*>(p + 48 * F);
                s0 += x0.x; q0 = fmaf(x0.x, x0.x, q0);
                s1 += x0.y; q1 = fmaf(x0.y, x0.y, q1);
                s2 += x0.z; q2 = fmaf(x0.z, x0.z, q2);
                s3 += x0.w; q3 = fmaf(x0.w, x0.w, q3);
                s0 += x1.x; q0 = fmaf(x1.x, x1.x, q0);
                s1 += x1.y; q1 = fmaf(x1.y, x1.y, q1);
                s2 += x1.z; q2 = fmaf(x1.z, x1.z, q2);
                s3 += x1.w; q3 = fmaf(x1.w, x1.w, q3);
                s0 += x2.x; q0 = fmaf(x2.x, x2.x, q0);
                s1 += x2.y; q1 = fmaf(x2.y, x2.y, q1);
                s2 += x2.z; q2 = fmaf(x2.z, x2.z, q2);
                s3 += x2.w; q3 = fmaf(x2.w, x2.w, q3);
                s0 += x3.x; q0 = fmaf(x3.x, x3.x, q0);
                s1 += x3.y; q1 = fmaf(x3.y, x3.y, q1);
                s2 += x3.z; q2 = fmaf(x3.z, x3.z, q2);
                s3 += x3.w; q3 = fmaf(x3.w, x3.w, q3);
            }
            for (; base + 16 <= send; base += 16, p += 16 * F) {
                const float4 x = *reinterpret_cast<const float4*>(p);
                s0 += x.x; q0 = fmaf(x.x, x.x, q0);
                s1 += x.y; q1 = fmaf(x.y, x.y, q1);
                s2 += x.z; q2 = fmaf(x.z, x.z, q2);
                s3 += x.w; q3 = fmaf(x.w, x.w, q3);
            }
            if (base + subrow < send) {              // segment tail (<16 rows)
                const float4 x = *reinterpret_cast<const float4*>(p);
                s0 += x.x; q0 = fmaf(x.x, x.x, q0);
                s1 += x.y; q1 = fmaf(x.y, x.y, q1);
                s2 += x.z; q2 = fmaf(x.z, x.z, q2);
                s3 += x.w; q3 = fmaf(x.w, x.w, q3);
            }
            // butterfly over lane-bits 1..5: lane0 -> groups 0..3, lane1 -> groups 4..7
            #pragma unroll
            for (int m = 2; m <= 32; m <<= 1) {
                s0 += __shfl_xor(s0, m); s1 += __shfl_xor(s1, m);
                s2 += __shfl_xor(s2, m); s3 += __shfl_xor(s3, m);
                q0 += __shfl_xor(q0, m); q1 += __shfl_xor(q1, m);
                q2 += __shfl_xor(q2, m); q3 += __shfl_xor(q3, m);
            }
            if (lane < 2) {
                float* ps = &lsum[b * G + lane * 4];
                float* pq = &lsq [b * G + lane * 4];
                atomicAdd(ps + 0, s0); atomicAdd(ps + 1, s1);
                atomicAdd(ps + 2, s2); atomicAdd(ps + 3, s3);
                atomicAdd(pq + 0, q0); atomicAdd(pq + 1, q1);
                atomicAdd(pq + 2, q2); atomicAdd(pq + 3, q3);
            }
            cur = send;
        }
    }
    __syncthreads();
    if (t < NB * G) {
        const int slot = (int)blockIdx.x & (NSLOT - 1);
        atomicAdd(&gsum[slot * NB * G + t], lsum[t]);
        atomicAdd(&gsq [slot * NB * G + t], lsq [t]);
    }
}

// --- Kernel C: normalize, REVERSED traversal (anti-LRU vs the output write
// stream; picks up each XCD's L2 tail from stats). Per-segment register
// coefficients; hot loop = temporal load float4 -> 4 fma -> nt store. ---
__global__ __launch_bounds__(BLK) void gn_norm(
        const float* __restrict__ feats, const int* __restrict__ off_g, int n,
        const float* __restrict__ gsum, const float* __restrict__ gsq,
        const float* __restrict__ gamma, const float* __restrict__ beta,
        float* __restrict__ out) {
    __shared__ int soff[NB + 1];
    const int t = threadIdx.x;
    if (t < NB + 1) soff[t] = off_g[t];
    __syncthreads();

    const int rpb  = (n + GRID - 1) / GRID;
    const int row0 = (int)blockIdx.x * rpb;
    const int row1 = min(n, row0 + rpb);
    if (row0 >= row1) return;

    const int quad   = t & 15;
    const int subrow = t >> 4;
    const float4 gm = *reinterpret_cast<const float4*>(gamma + quad * 4);
    const float4 bt = *reinterpret_cast<const float4*>(beta  + quad * 4);

    int b = NB - 1, e = row1;
    while (e > row0) {
        while (soff[b] >= e) --b;                 // rows e-1 belong to batch b
        const int sstart = max(row0, soff[b]);    // segment = [sstart, e), uniform b
        // sum the NSLOT shadow copies for this lane's 4 groups ((quad&1)*4 ..+3)
        f32x4 sm = {0.f, 0.f, 0.f, 0.f}, sq = {0.f, 0.f, 0.f, 0.f};
        #pragma unroll
        for (int k = 0; k < NSLOT; ++k) {
            sm += *reinterpret_cast<const f32x4*>(gsum + k * NB * G + b * G + (quad & 1) * 4);
            sq += *reinterpret_cast<const f32x4*>(gsq  + k * NB * G + b * G + (quad & 1) * 4);
        }
        const float cnt = (float)max((soff[b + 1] - soff[b]) * (F / G), 1);
        const float rc  = 1.0f / cnt;
        f32x4 a, c;
        {
            const float m0 = sm.x * rc, m1 = sm.y * rc, m2 = sm.z * rc, m3 = sm.w * rc;
            const float v0 = fmaxf(sq.x * rc - m0 * m0, 0.f);
            const float v1 = fmaxf(sq.y * rc - m1 * m1, 0.f);
            const float v2 = fmaxf(sq.z * rc - m2 * m2, 0.f);
            const float v3 = fmaxf(sq.w * rc - m3 * m3, 0.f);
            a.x = gm.x / sqrtf(v0 + GN_EPS); a.y = gm.y / sqrtf(v1 + GN_EPS);
            a.z = gm.z / sqrtf(v2 + GN_EPS); a.w = gm.w / sqrtf(v3 + GN_EPS);
            c.x = fmaf(-m0, a.x, bt.x); c.y = fmaf(-m1, a.y, bt.y);
            c.z = fmaf(-m2, a.z, bt.z); c.w = fmaf(-m3, a.w, bt.w);
        }
        int hi = e;
        for (; hi - sstart >= 64; hi -= 64) {     // 64-row tiles, descending
            const float* p  = feats + (size_t)(hi - 64 + subrow) * F + quad * 4;
            float*       po = out   + (size_t)(hi - 64 + subrow) * F + quad * 4;
            const f32x4 x0 = *reinterpret_cast<const f32x4*>(p);
            const f32x4 x1 = *reinterpret_cast<const f32x4*>(p + 16 * F);
            const f32x4 x2 = *reinterpret_cast<const f32x4*>(p + 32 * F);
            const f32x4 x3 = *reinterpret_cast<const f32x4*>(p + 48 * F);
            f32x4 o0, o1, o2, o3;
            o0.x = fmaf(x0.x, a.x, c.x); o0.y = fmaf(x0.y, a.y, c.y);
            o0.z = fmaf(x0.z, a.z, c.z); o0.w = fmaf(x0.w, a.w, c.w);
            o1.x = fmaf(x1.x, a.x, c.x); o1.y = fmaf(x1.y, a.y, c.y);
            o1.z = fmaf(x1.z, a.z, c.z); o1.w = fmaf(x1.w, a.w, c.w);
            o2.x = fmaf(x2.x, a.x, c.x); o2.y = fmaf(x2.y, a.y, c.y);
            o2.z = fmaf(x2.z, a.z, c.z); o2.w = fmaf(x2.w, a.w, c.w);
            o3.x = fmaf(x3.x, a.x, c.x); o3.y = fmaf(x3.y, a.y, c.y);
            o3.z = fmaf(x3.z, a.z, c.z); o3.w = fmaf(x3.w, a.w, c.w);
            __builtin_nontemporal_store(o0, reinterpret_cast<f32x4*>(po));
            __builtin_nontemporal_store(o1, reinterpret_cast<f32x4*>(po + 16 * F));
            __builtin_nontemporal_store(o2, reinterpret_cast<f32x4*>(po + 32 * F));
            __builtin_nontemporal_store(o3, reinterpret_cast<f32x4*>(po + 48 * F));
        }
        for (; hi - sstart >= 16; hi -= 16) {     // 16-row tiles, descending
            const float* p  = feats + (size_t)(hi - 16 + subrow) * F + quad * 4;
            float*       po = out   + (size_t)(hi - 16 + subrow) * F + quad * 4;
            const f32x4 x = *reinterpret_cast<const f32x4*>(p);
            f32x4 o;
            o.x = fmaf(x.x, a.x, c.x); o.y = fmaf(x.y, a.y, c.y);
            o.z = fmaf(x.z, a.z, c.z); o.w = fmaf(x.w, a.w, c.w);
            __builtin_nontemporal_store(o, reinterpret_cast<f32x4*>(po));
        }
        if (sstart + subrow < hi) {               // bottom tail (<16 rows)
            const float* p  = feats + (size_t)(sstart + subrow) * F + quad * 4;
            float*       po = out   + (size_t)(sstart + subrow) * F + quad * 4;
            const f32x4 x = *reinterpret_cast<const f32x4*>(p);
            f32x4 o;
            o.x = fmaf(x.x, a.x, c.x); o.y = fmaf(x.y, a.y, c.y);
            o.z = fmaf(x.z, a.z, c.z); o.w = fmaf(x.w, a.w, c.w);
            __builtin_nontemporal_store(o, reinterpret_cast<f32x4*>(po));
        }
        e = sstart;
    }
}

extern "C" void kernel_launch(void* const* d_in, const int* in_sizes, int n_in,
                              void* d_out, int out_size, void* d_ws, size_t ws_size,
                              hipStream_t stream) {
    const float* feats = (const float*)d_in[0];
    const int*   ids   = (const int*)  d_in[1];
    const float* gamma = (const float*)d_in[2];
    const float* beta  = (const float*)d_in[3];
    const int n = in_sizes[1];                     // N rows (batch_ids count)

    float* gsum = (float*)d_ws;                    // [NSLOT][NB*G]
    float* gsq  = gsum + NSLOT * NB * G;           // [NSLOT][NB*G]
    int*   off  = (int*)(gsq + NSLOT * NB * G);    // [NB+1]

    // ws is poisoned 0xAA and never re-poisoned between replays -> prep zeroes
    // the shadow accumulators and builds the offset table each call.
    gn_prep <<<1, BLK, 0, stream>>>(ids, n, off, gsum);
    gn_stats<<<GRID, BLK, 0, stream>>>(feats, off, n, gsum, gsq);
    gn_norm <<<GRID, BLK, 0, stream>>>(feats, off, n, gsum, gsq, gamma, beta, (float*)d_out);
}